// Round 7
// baseline (102.776 us; speedup 1.0000x reference)
//
#include <hip/hip_runtime.h>

#define BB 4096
#define TT 80
#define VV 10000
#define EE 100
#define HH 64
#define STR 68   // fp16 row stride: 136 B/row; read/write bursts at bank minimum
#define CTR_OFF (VV * HH * 4)   // counter offset in workspace (after emb2 table)

typedef _Float16 f16x8 __attribute__((ext_vector_type(8)));
typedef _Float16 f16x4 __attribute__((ext_vector_type(4)));
typedef __attribute__((ext_vector_type(4))) float f4v;   // 4 fp32

// Transposed compute: D = A(W^T frag) * B(state frag) + C -> lane holds
// (batch row = l&15, 4 adjacent hidden cols = 4*(l>>4)+q)
#define MFMA(w, s, c) __builtin_amdgcn_mfma_f32_16x16x32_f16((w), (s), (c), 0, 0, 0)

// Raw barrier: drains LDS ops (lgkm) but lets global loads stay in flight.
#define BAR() do { asm volatile("s_waitcnt lgkmcnt(0)" ::: "memory"); \
                   __builtin_amdgcn_s_barrier();                      \
                   asm volatile("" ::: "memory"); } while (0)

// tanh(x) = 1 - 2/(exp(2x)+1). No clamp: +inf -> 1, -inf -> -1.
__device__ __forceinline__ float fast_tanh(float x) {
    float e = __builtin_amdgcn_exp2f(x * 2.8853900817779268f); // exp(2x)
    return 1.0f - 2.0f * __builtin_amdgcn_rcpf(e + 1.0f);
}

// Weight fragment (hi/lo fp16) for W[k][c]: frag elem i <- W[32*kf + 8*g + i][c]
__device__ __forceinline__ void load_wfrag(const float* __restrict__ W, int kf, int g,
                                           int c, f16x8& hi, f16x8& lo) {
    union { _Float16 h[8]; f16x8 v; } th, tl;
#pragma unroll
    for (int i = 0; i < 8; ++i) {
        float wv = W[(32 * kf + 8 * g + i) * HH + c];
        _Float16 hf = (_Float16)wv;          // RNE
        th.h[i] = hf;
        tl.h[i] = (_Float16)(wv - (float)hf);
    }
    hi = th.v;
    lo = tl.v;
}

// Fused kernel: emb2 slice -> device-wide sync -> RNN pipeline.
// 256 blocks x 256 thr, launch_bounds(256,1): device capacity >= 2 blocks/CU
// => all 256 blocks resident from dispatch => spin-sync is deadlock-free.
__global__ __launch_bounds__(256, 1) void rnn_fused(
    const int* __restrict__ tokens, const float* __restrict__ emb,
    const float* __restrict__ Wx0, const float* __restrict__ b0,
    const float* __restrict__ Wh0, const float* __restrict__ Wx1,
    const float* __restrict__ Wh1, const float* __restrict__ b1,
    const float* __restrict__ Wout, const float* __restrict__ bout,
    float* __restrict__ emb2, int* __restrict__ ctr,
    float* __restrict__ out) {
    __shared__ __align__(16) _Float16 H0[2][16][STR];
    __shared__ __align__(16) _Float16 H1[2][16][STR];
    __shared__ __align__(16) int tokT[TT][16];   // [t][row], byte-scaled (<<8)
    __shared__ float Pred[4][16];

    const int tid = threadIdx.x;
    const int wid = tid >> 6;        // 0..3 : hidden-column tile
    const int l = tid & 63;
    const int g = l >> 4;
    const int r16 = l & 15;          // batch/vocab row within tile (A-m / B-n / D-n)
    const int c = 16 * wid + r16;    // weight column for A-fragment loads
    const int jcol = 16 * wid + 4 * g;  // my 4 output cols (D-m)
    const int R = blockIdx.x * 16;   // base batch row

    // ================= emb2 slice: rows [48*bid, 48*bid+48) =================
    // Same transposed-MFMA pattern as the main loop; hi-fp16 only (x error
    // ~3e-5, far below the fp16-state noise already in the pipeline).
    {
        const int v0 = blockIdx.x * 48;
        if (v0 < VV) {
            f16x8 wa[4];   // Wx0^T hi frags, K = 112 (zero-pad e >= 100)
#pragma unroll
            for (int kf = 0; kf < 4; ++kf) {
                union { _Float16 h[8]; f16x8 v; } t;
#pragma unroll
                for (int i = 0; i < 8; ++i) {
                    int e = 32 * kf + 8 * g + i;
                    t.h[i] = (e < EE) ? (_Float16)Wx0[e * HH + c] : (_Float16)0.f;
                }
                wa[kf] = t.v;
            }
            const f4v b0v = *(const f4v*)&b0[jcol];
#pragma unroll
            for (int t3 = 0; t3 < 3; ++t3) {
                int vr = v0 + 16 * t3 + r16;
                const float* er = emb + (size_t)(vr < VV ? vr : 0) * EE;
                f4v acc = b0v;
#pragma unroll
                for (int kf = 0; kf < 4; ++kf) {
                    union { _Float16 h[8]; f16x8 v; } tb;
#pragma unroll
                    for (int i = 0; i < 8; ++i) {
                        int e = 32 * kf + 8 * g + i;
                        tb.h[i] = (e < EE) ? (_Float16)er[e] : (_Float16)0.f;
                    }
                    acc = MFMA(wa[kf], tb.v, acc);
                }
                if (vr < VV) *(f4v*)&emb2[(size_t)vr * HH + jcol] = acc;
            }
        }
        __threadfence();              // release: slice stores visible agent-wide
        BAR();                        // whole block done
        if (tid == 0) atomicAdd(ctr, 1);
    }

    // ---- rnn prologue (overlaps other blocks' slices / the spin) ----
    for (int i = tid; i < 16 * TT; i += 256) {
        int r = i / TT, t = i - r * TT;              // coalesced global read
        tokT[t][r] = tokens[R * TT + i] << 8;
    }

    f16x8 wh0h[2], wh0l[2], wx1h[2], wx1l[2], wh1h[2], wh1l[2];
    load_wfrag(Wh0, 0, g, c, wh0h[0], wh0l[0]);
    load_wfrag(Wh0, 1, g, c, wh0h[1], wh0l[1]);
    load_wfrag(Wx1, 0, g, c, wx1h[0], wx1l[0]);
    load_wfrag(Wx1, 1, g, c, wx1h[1], wx1l[1]);
    load_wfrag(Wh1, 0, g, c, wh1h[0], wh1l[0]);
    load_wfrag(Wh1, 1, g, c, wh1h[1], wh1l[1]);
    const f4v b1v = *(const f4v*)&b1[jcol];
    const f4v wov = *(const f4v*)&Wout[jcol];
    const f4v z4 = {0.f, 0.f, 0.f, 0.f};
    const char* ebase = (const char*)emb2 + (size_t)jcol * 4;

    // ---- device-wide wait: emb2 fully built ----
    if (tid == 0) {
        while (__hip_atomic_load(ctr, __ATOMIC_RELAXED,
                                 __HIP_MEMORY_SCOPE_AGENT) < 256)
            __builtin_amdgcn_s_sleep(8);
    }
    BAR();                            // releases block; also orders tokT stores
    __threadfence();                  // acquire: invalidate caches for emb2 reads

    f16x8 a0[2] = {(f16x8)0, (f16x8)0};   // h0(p-1)^T fragments (kf=0,1)
    f16x8 a1[2] = {(f16x8)0, (f16x8)0};   // h1(p-2)^T fragments

    f4v xc, xn;
    {
        int tb0 = tokT[0][r16];
        int tb1 = tokT[1][r16];
        xc = *(const f4v*)(ebase + tb0);   // x(0)[r16][jcol..jcol+3]
        xn = *(const f4v*)(ebase + tb1);
    }

    // ---- phase 0: h0(0) = tanh(x0) ----
    {
        f16x4 ph;
#pragma unroll
        for (int q = 0; q < 4; ++q) ph[q] = (_Float16)fast_tanh(xc[q]);
        *(f16x4*)&H0[0][r16][jcol] = ph;           // one b64 write
    }
    xc = xn;
    BAR();
    a0[0] = *(const f16x8*)&H0[0][r16][8 * g];
    a0[1] = *(const f16x8*)&H0[0][r16][32 + 8 * g];
    // a1 stays zero (h1(-1) = 0)

    // ---- main loop p = 1..TT-2 ----
#pragma unroll 2
    for (int p = 1; p <= TT - 2; ++p) {
        const int par = p & 1;
        // prefetch x(p+1): one dwordx4 gather; floats across BAR to next use
        int tb = tokT[p + 1][r16];
        xn = *(const f4v*)(ebase + tb);
        // L0: h0(p)^T — 2 chains of 2
        f4v A1 = xc;
        A1 = MFMA(wh0h[0], a0[0], A1);
        A1 = MFMA(wh0h[1], a0[1], A1);
        f4v A2 = MFMA(wh0l[0], a0[0], z4);
        A2 = MFMA(wh0l[1], a0[1], A2);
        // L1: h1(p-1)^T — 4 chains of 2 (reuses a0 fragments)
        f4v C1 = b1v;
        C1 = MFMA(wx1h[0], a0[0], C1);
        C1 = MFMA(wx1h[1], a0[1], C1);
        f4v C2 = MFMA(wx1l[0], a0[0], z4);
        C2 = MFMA(wx1l[1], a0[1], C2);
        f4v C3 = MFMA(wh1h[0], a1[0], z4);
        C3 = MFMA(wh1h[1], a1[1], C3);
        f4v C4 = MFMA(wh1l[0], a1[0], z4);
        C4 = MFMA(wh1l[1], a1[1], C4);
        f4v acc0 = A1 + A2;
        f4v acc1 = (C1 + C2) + (C3 + C4);
        f16x4 p0, p1;
#pragma unroll
        for (int q = 0; q < 4; ++q) {
            p0[q] = (_Float16)fast_tanh(acc0[q]);
            p1[q] = (_Float16)fast_tanh(acc1[q]);
        }
        *(f16x4*)&H0[par][r16][jcol] = p0;         // one b64 write each
        *(f16x4*)&H1[par][r16][jcol] = p1;
        xc = xn;
        BAR();
        a0[0] = *(const f16x8*)&H0[par][r16][8 * g];
        a0[1] = *(const f16x8*)&H0[par][r16][32 + 8 * g];
        a1[0] = *(const f16x8*)&H1[par][r16][8 * g];
        a1[1] = *(const f16x8*)&H1[par][r16][32 + 8 * g];
    }

    // ---- p = TT-1 = 79 (par 1): both layers, no prefetch ----
    {
        f4v A1 = xc;
        A1 = MFMA(wh0h[0], a0[0], A1);
        A1 = MFMA(wh0h[1], a0[1], A1);
        f4v A2 = MFMA(wh0l[0], a0[0], z4);
        A2 = MFMA(wh0l[1], a0[1], A2);
        f4v C1 = b1v;
        C1 = MFMA(wx1h[0], a0[0], C1);
        C1 = MFMA(wx1h[1], a0[1], C1);
        f4v C2 = MFMA(wx1l[0], a0[0], z4);
        C2 = MFMA(wx1l[1], a0[1], C2);
        f4v C3 = MFMA(wh1h[0], a1[0], z4);
        C3 = MFMA(wh1h[1], a1[1], C3);
        f4v C4 = MFMA(wh1l[0], a1[0], z4);
        C4 = MFMA(wh1l[1], a1[1], C4);
        f4v acc0 = A1 + A2;
        f4v acc1 = (C1 + C2) + (C3 + C4);
        f16x4 p0, p1;
#pragma unroll
        for (int q = 0; q < 4; ++q) {
            p0[q] = (_Float16)fast_tanh(acc0[q]);
            p1[q] = (_Float16)fast_tanh(acc1[q]);
        }
        *(f16x4*)&H0[1][r16][jcol] = p0;
        *(f16x4*)&H1[1][r16][jcol] = p1;
        BAR();
        a0[0] = *(const f16x8*)&H0[1][r16][8 * g];
        a0[1] = *(const f16x8*)&H0[1][r16][32 + 8 * g];
        a1[0] = *(const f16x8*)&H1[1][r16][8 * g];
        a1[1] = *(const f16x8*)&H1[1][r16][32 + 8 * g];
    }

    // ---- p = TT = 80: L1 only -> h1(79) stays in registers ----
    {
        f4v C1 = b1v;
        C1 = MFMA(wx1h[0], a0[0], C1);
        C1 = MFMA(wx1h[1], a0[1], C1);
        f4v C2 = MFMA(wx1l[0], a0[0], z4);
        C2 = MFMA(wx1l[1], a0[1], C2);
        f4v C3 = MFMA(wh1h[0], a1[0], z4);
        C3 = MFMA(wh1h[1], a1[1], C3);
        f4v C4 = MFMA(wh1l[0], a1[0], z4);
        C4 = MFMA(wh1l[1], a1[1], C4);
        f4v acc1 = (C1 + C2) + (C3 + C4);
        // Epilogue in-register: lane holds h1(79)[r16][jcol..jcol+3]
        float pp = fast_tanh(acc1[0]) * wov[0];
        pp = fmaf(fast_tanh(acc1[1]), wov[1], pp);
        pp = fmaf(fast_tanh(acc1[2]), wov[2], pp);
        pp = fmaf(fast_tanh(acc1[3]), wov[3], pp);
        pp += __shfl_xor(pp, 16, 64);   // sum over g-groups
        pp += __shfl_xor(pp, 32, 64);
        if (l < 16) Pred[wid][l] = pp;
        BAR();
        if (tid < 16) {
            float logit = Pred[0][tid] + Pred[1][tid] + Pred[2][tid] +
                          Pred[3][tid] + bout[0];
            out[R + tid] = __builtin_amdgcn_rcpf(
                1.0f + __builtin_amdgcn_exp2f(-1.4426950408889634f * logit));
        }
    }
}

extern "C" void kernel_launch(void* const* d_in, const int* in_sizes, int n_in,
                              void* d_out, int out_size, void* d_ws, size_t ws_size,
                              hipStream_t stream) {
    const int*   tokens = (const int*)  d_in[0];
    const float* emb    = (const float*)d_in[1];
    const float* Wx0    = (const float*)d_in[2];
    const float* Wh0    = (const float*)d_in[3];
    const float* b0     = (const float*)d_in[4];
    const float* Wx1    = (const float*)d_in[5];
    const float* Wh1    = (const float*)d_in[6];
    const float* b1     = (const float*)d_in[7];
    const float* Wout   = (const float*)d_in[8];
    const float* bout   = (const float*)d_in[9];
    float* out  = (float*)d_out;
    float* emb2 = (float*)d_ws;                       // VV*HH floats = 2.56 MB
    int*   ctr  = (int*)((char*)d_ws + CTR_OFF);      // sync counter

    hipMemsetAsync(ctr, 0, 4, stream);                // airtight ctr = 0
    rnn_fused<<<BB / 16, 256, 0, stream>>>(tokens, emb, Wx0, b0, Wh0, Wx1,
                                           Wh1, b1, Wout, bout, emb2, ctr, out);
}

// Round 8
// 47.742 us; speedup vs baseline: 2.1527x; 2.1527x over previous
//
#include <hip/hip_runtime.h>

#define BB 4096
#define TT 80
#define VV 10000
#define EE 100
#define HH 64
#define STR 68   // fp16 row stride: 136 B/row; read/write bursts at bank minimum

typedef _Float16 f16x8 __attribute__((ext_vector_type(8)));
typedef _Float16 f16x4 __attribute__((ext_vector_type(4)));
typedef __attribute__((ext_vector_type(4))) float f4v;   // 4 fp32

// Transposed compute: D = A(W^T frag) * B(state frag) + C -> lane holds
// (batch row = l&15, 4 adjacent hidden cols = 4*(l>>4)+q)
#define MFMA(w, s, c) __builtin_amdgcn_mfma_f32_16x16x32_f16((w), (s), (c), 0, 0, 0)

// Raw barrier: drains LDS ops (lgkm) but lets global loads stay in flight.
#define BAR() do { asm volatile("s_waitcnt lgkmcnt(0)" ::: "memory"); \
                   __builtin_amdgcn_s_barrier();                      \
                   asm volatile("" ::: "memory"); } while (0)

// tanh(x) = 1 - 2/(exp(2x)+1). No clamp: +inf -> 1, -inf -> -1.
__device__ __forceinline__ float fast_tanh(float x) {
    float e = __builtin_amdgcn_exp2f(x * 2.8853900817779268f); // exp(2x)
    return 1.0f - 2.0f * __builtin_amdgcn_rcpf(e + 1.0f);
}

// Weight fragment (hi/lo fp16) for W[k][c]: frag elem i <- W[32*kf + 8*g + i][c]
__device__ __forceinline__ void load_wfrag(const float* __restrict__ W, int kf, int g,
                                           int c, f16x8& hi, f16x8& lo) {
    union { _Float16 h[8]; f16x8 v; } th, tl;
#pragma unroll
    for (int i = 0; i < 8; ++i) {
        float wv = W[(32 * kf + 8 * g + i) * HH + c];
        _Float16 hf = (_Float16)wv;          // RNE
        th.h[i] = hf;
        tl.h[i] = (_Float16)(wv - (float)hf);
    }
    hi = th.v;
    lo = tl.v;
}

// emb2h[v][j] = fp16( b0[j] + sum_e emb[v][e] * Wx0[e][j] )
// Transposed-MFMA version (fragment patterns verified in R6/R7): 625 blocks,
// 4 waves; each wave computes 16 vocab rows x its 16 hidden cols.
// hi-fp16 weights/inputs only: injected error ~3e-5, far below fp16-state noise.
__global__ __launch_bounds__(256) void emb2_kernel(const float* __restrict__ emb,
                                                   const float* __restrict__ Wx0,
                                                   const float* __restrict__ b0,
                                                   _Float16* __restrict__ emb2h) {
    const int tid = threadIdx.x;
    const int wid = tid >> 6;
    const int l = tid & 63;
    const int g = l >> 4;
    const int r16 = l & 15;
    const int c = 16 * wid + r16;       // weight column (A-fragment m index)
    const int jcol = 16 * wid + 4 * g;  // my 4 output cols
    const int vr = blockIdx.x * 16 + r16;   // my vocab row (B/D n index); VV%16==0

    f16x8 wa[4];   // Wx0^T hi frags, K = 128 (zero-pad e >= 100)
#pragma unroll
    for (int kf = 0; kf < 4; ++kf) {
        union { _Float16 h[8]; f16x8 v; } t;
#pragma unroll
        for (int i = 0; i < 8; ++i) {
            int e = 32 * kf + 8 * g + i;
            t.h[i] = (e < EE) ? (_Float16)Wx0[e * HH + c] : (_Float16)0.f;
        }
        wa[kf] = t.v;
    }
    const float* er = emb + (size_t)vr * EE;
    f4v acc = *(const f4v*)&b0[jcol];
#pragma unroll
    for (int kf = 0; kf < 4; ++kf) {
        union { _Float16 h[8]; f16x8 v; } tb;
#pragma unroll
        for (int i = 0; i < 8; ++i) {
            int e = 32 * kf + 8 * g + i;
            tb.h[i] = (e < EE) ? (_Float16)er[e] : (_Float16)0.f;
        }
        acc = MFMA(wa[kf], tb.v, acc);
    }
    f16x4 o;
#pragma unroll
    for (int q = 0; q < 4; ++q) o[q] = (_Float16)acc[q];
    *(f16x4*)&emb2h[(size_t)vr * HH + jcol] = o;
}

// Transposed-MFMA pipeline (R6 structure, unchanged sync): 256 blocks, 4 waves,
// 16 rows/block. Wave owns one 16-hidden-col tile of BOTH layers:
//   h0(p)^T   = tanh(x(p)^T + Wh0^T @ h0(p-1)^T)
//   h1(p-1)^T = tanh(b1 + Wx1^T @ h0(p-1)^T + Wh1^T @ h1(p-2)^T)
// fp16 state in double-buffered LDS; hi/lo fp16 weights (12 MFMA/phase);
// one raw barrier per phase. x is gathered as f16x4 (8 B/lane) and carried
// RAW across the barrier; cvt to fp32 happens at use so the gather's vmcnt
// wait lands a full phase after issue.
__global__ __launch_bounds__(256, 1) void rnn_pipe(
    const int* __restrict__ tokens, const _Float16* __restrict__ emb2,
    const float* __restrict__ Wh0, const float* __restrict__ Wx1,
    const float* __restrict__ Wh1, const float* __restrict__ b1,
    const float* __restrict__ Wout, const float* __restrict__ bout,
    float* __restrict__ out) {
    __shared__ __align__(16) _Float16 H0[2][16][STR];
    __shared__ __align__(16) _Float16 H1[2][16][STR];
    __shared__ __align__(16) int tokT[TT][16];   // [t][row], byte-scaled (<<7)
    __shared__ float Pred[4][16];

    const int tid = threadIdx.x;
    const int wid = tid >> 6;        // 0..3 : hidden-column tile
    const int l = tid & 63;
    const int g = l >> 4;
    const int r16 = l & 15;          // my batch row
    const int c = 16 * wid + r16;    // weight column for A-fragment loads
    const int jcol = 16 * wid + 4 * g;  // my 4 output cols
    const int R = blockIdx.x * 16;   // base batch row

    for (int i = tid; i < 16 * TT; i += 256) {
        int r = i / TT, t = i - r * TT;              // coalesced global read
        tokT[t][r] = tokens[R * TT + i] << 7;        // row stride 64 fp16 = 128 B
    }

    f16x8 wh0h[2], wh0l[2], wx1h[2], wx1l[2], wh1h[2], wh1l[2];
    load_wfrag(Wh0, 0, g, c, wh0h[0], wh0l[0]);
    load_wfrag(Wh0, 1, g, c, wh0h[1], wh0l[1]);
    load_wfrag(Wx1, 0, g, c, wx1h[0], wx1l[0]);
    load_wfrag(Wx1, 1, g, c, wx1h[1], wx1l[1]);
    load_wfrag(Wh1, 0, g, c, wh1h[0], wh1l[0]);
    load_wfrag(Wh1, 1, g, c, wh1h[1], wh1l[1]);
    const f4v b1v = *(const f4v*)&b1[jcol];
    const f4v wov = *(const f4v*)&Wout[jcol];
    const f4v z4 = {0.f, 0.f, 0.f, 0.f};
    const char* ebase = (const char*)emb2 + (size_t)jcol * 2;

    BAR();   // tokens staged

    f16x8 a0[2] = {(f16x8)0, (f16x8)0};   // h0(p-1)^T fragments (kf=0,1)
    f16x8 a1[2] = {(f16x8)0, (f16x8)0};   // h1(p-2)^T fragments

    f16x4 xc, xn;   // raw fp16 gathers; converted at use
    {
        int tb0 = tokT[0][r16];
        int tb1 = tokT[1][r16];
        xc = *(const f16x4*)(ebase + tb0);   // x(0)[r16][jcol..jcol+3]
        xn = *(const f16x4*)(ebase + tb1);
    }

    // ---- phase 0: h0(0) = tanh(x0) ----
    {
        f16x4 ph;
#pragma unroll
        for (int q = 0; q < 4; ++q) ph[q] = (_Float16)fast_tanh((float)xc[q]);
        *(f16x4*)&H0[0][r16][jcol] = ph;           // one b64 write
    }
    xc = xn;
    BAR();
    a0[0] = *(const f16x8*)&H0[0][r16][8 * g];
    a0[1] = *(const f16x8*)&H0[0][r16][32 + 8 * g];
    // a1 stays zero (h1(-1) = 0)

    // ---- main loop p = 1..TT-2 ----
#pragma unroll 2
    for (int p = 1; p <= TT - 2; ++p) {
        const int par = p & 1;
        // prefetch x(p+1): one 8 B gather; floats across BAR to next-phase use
        int tb = tokT[p + 1][r16];
        xn = *(const f16x4*)(ebase + tb);
        // L0: h0(p)^T — 2 chains of 2
        f4v A1 = {(float)xc[0], (float)xc[1], (float)xc[2], (float)xc[3]};
        A1 = MFMA(wh0h[0], a0[0], A1);
        A1 = MFMA(wh0h[1], a0[1], A1);
        f4v A2 = MFMA(wh0l[0], a0[0], z4);
        A2 = MFMA(wh0l[1], a0[1], A2);
        // L1: h1(p-1)^T — 4 chains of 2 (reuses a0 fragments)
        f4v C1 = b1v;
        C1 = MFMA(wx1h[0], a0[0], C1);
        C1 = MFMA(wx1h[1], a0[1], C1);
        f4v C2 = MFMA(wx1l[0], a0[0], z4);
        C2 = MFMA(wx1l[1], a0[1], C2);
        f4v C3 = MFMA(wh1h[0], a1[0], z4);
        C3 = MFMA(wh1h[1], a1[1], C3);
        f4v C4 = MFMA(wh1l[0], a1[0], z4);
        C4 = MFMA(wh1l[1], a1[1], C4);
        f4v acc0 = A1 + A2;
        f4v acc1 = (C1 + C2) + (C3 + C4);
        f16x4 p0, p1;
#pragma unroll
        for (int q = 0; q < 4; ++q) {
            p0[q] = (_Float16)fast_tanh(acc0[q]);
            p1[q] = (_Float16)fast_tanh(acc1[q]);
        }
        *(f16x4*)&H0[par][r16][jcol] = p0;         // one b64 write each
        *(f16x4*)&H1[par][r16][jcol] = p1;
        xc = xn;
        BAR();
        a0[0] = *(const f16x8*)&H0[par][r16][8 * g];
        a0[1] = *(const f16x8*)&H0[par][r16][32 + 8 * g];
        a1[0] = *(const f16x8*)&H1[par][r16][8 * g];
        a1[1] = *(const f16x8*)&H1[par][r16][32 + 8 * g];
    }

    // ---- p = TT-1 = 79 (par 1): both layers, no prefetch ----
    {
        f4v A1 = {(float)xc[0], (float)xc[1], (float)xc[2], (float)xc[3]};
        A1 = MFMA(wh0h[0], a0[0], A1);
        A1 = MFMA(wh0h[1], a0[1], A1);
        f4v A2 = MFMA(wh0l[0], a0[0], z4);
        A2 = MFMA(wh0l[1], a0[1], A2);
        f4v C1 = b1v;
        C1 = MFMA(wx1h[0], a0[0], C1);
        C1 = MFMA(wx1h[1], a0[1], C1);
        f4v C2 = MFMA(wx1l[0], a0[0], z4);
        C2 = MFMA(wx1l[1], a0[1], C2);
        f4v C3 = MFMA(wh1h[0], a1[0], z4);
        C3 = MFMA(wh1h[1], a1[1], C3);
        f4v C4 = MFMA(wh1l[0], a1[0], z4);
        C4 = MFMA(wh1l[1], a1[1], C4);
        f4v acc0 = A1 + A2;
        f4v acc1 = (C1 + C2) + (C3 + C4);
        f16x4 p0, p1;
#pragma unroll
        for (int q = 0; q < 4; ++q) {
            p0[q] = (_Float16)fast_tanh(acc0[q]);
            p1[q] = (_Float16)fast_tanh(acc1[q]);
        }
        *(f16x4*)&H0[1][r16][jcol] = p0;
        *(f16x4*)&H1[1][r16][jcol] = p1;
        BAR();
        a0[0] = *(const f16x8*)&H0[1][r16][8 * g];
        a0[1] = *(const f16x8*)&H0[1][r16][32 + 8 * g];
        a1[0] = *(const f16x8*)&H1[1][r16][8 * g];
        a1[1] = *(const f16x8*)&H1[1][r16][32 + 8 * g];
    }

    // ---- p = TT = 80: L1 only -> h1(79) stays in registers ----
    {
        f4v C1 = b1v;
        C1 = MFMA(wx1h[0], a0[0], C1);
        C1 = MFMA(wx1h[1], a0[1], C1);
        f4v C2 = MFMA(wx1l[0], a0[0], z4);
        C2 = MFMA(wx1l[1], a0[1], C2);
        f4v C3 = MFMA(wh1h[0], a1[0], z4);
        C3 = MFMA(wh1h[1], a1[1], C3);
        f4v C4 = MFMA(wh1l[0], a1[0], z4);
        C4 = MFMA(wh1l[1], a1[1], C4);
        f4v acc1 = (C1 + C2) + (C3 + C4);
        // Epilogue in-register: lane holds h1(79)[r16][jcol..jcol+3]
        float pp = fast_tanh(acc1[0]) * wov[0];
        pp = fmaf(fast_tanh(acc1[1]), wov[1], pp);
        pp = fmaf(fast_tanh(acc1[2]), wov[2], pp);
        pp = fmaf(fast_tanh(acc1[3]), wov[3], pp);
        pp += __shfl_xor(pp, 16, 64);   // sum over g-groups
        pp += __shfl_xor(pp, 32, 64);
        if (l < 16) Pred[wid][l] = pp;
        BAR();
        if (tid < 16) {
            float logit = Pred[0][tid] + Pred[1][tid] + Pred[2][tid] +
                          Pred[3][tid] + bout[0];
            out[R + tid] = __builtin_amdgcn_rcpf(
                1.0f + __builtin_amdgcn_exp2f(-1.4426950408889634f * logit));
        }
    }
}

extern "C" void kernel_launch(void* const* d_in, const int* in_sizes, int n_in,
                              void* d_out, int out_size, void* d_ws, size_t ws_size,
                              hipStream_t stream) {
    const int*   tokens = (const int*)  d_in[0];
    const float* emb    = (const float*)d_in[1];
    const float* Wx0    = (const float*)d_in[2];
    const float* Wh0    = (const float*)d_in[3];
    const float* b0     = (const float*)d_in[4];
    const float* Wx1    = (const float*)d_in[5];
    const float* Wh1    = (const float*)d_in[6];
    const float* b1     = (const float*)d_in[7];
    const float* Wout   = (const float*)d_in[8];
    const float* bout   = (const float*)d_in[9];
    float* out  = (float*)d_out;
    _Float16* emb2h = (_Float16*)d_ws;   // VV*HH fp16 = 1.28 MB

    emb2_kernel<<<VV / 16, 256, 0, stream>>>(emb, Wx0, b0, emb2h);
    rnn_pipe<<<BB / 16, 256, 0, stream>>>(tokens, emb2h, Wh0, Wx1, Wh1, b1,
                                          Wout, bout, out);
}

// Round 9
// 40.886 us; speedup vs baseline: 2.5137x; 1.1677x over previous
//
#include <hip/hip_runtime.h>

#define BB 4096
#define TT 80
#define VV 10000
#define EE 100
#define HH 64
#define STR 68   // fp16 row stride: 136 B/row; read/write bursts at bank minimum

typedef _Float16 f16x8 __attribute__((ext_vector_type(8)));
typedef _Float16 f16x4 __attribute__((ext_vector_type(4)));
typedef __attribute__((ext_vector_type(4))) float f4v;   // 4 fp32

// Transposed compute: D = A(W^T frag) * B(state frag) + C -> lane holds
// (batch row = l&15, 4 adjacent hidden cols = 4*(l>>4)+q)
#define MFMA(w, s, c) __builtin_amdgcn_mfma_f32_16x16x32_f16((w), (s), (c), 0, 0, 0)

// Raw barrier: drains LDS ops (lgkm) but lets global loads stay in flight.
#define BAR() do { asm volatile("s_waitcnt lgkmcnt(0)" ::: "memory"); \
                   __builtin_amdgcn_s_barrier();                      \
                   asm volatile("" ::: "memory"); } while (0)

// tanh(x) = 1 - 2/(exp(2x)+1). No clamp: +inf -> 1, -inf -> -1.
__device__ __forceinline__ float fast_tanh(float x) {
    float e = __builtin_amdgcn_exp2f(x * 2.8853900817779268f); // exp(2x)
    return 1.0f - 2.0f * __builtin_amdgcn_rcpf(e + 1.0f);
}

// Weight fragment (hi/lo fp16) for W[k][c]: frag elem i <- W[32*kf + 8*g + i][c]
__device__ __forceinline__ void load_wfrag(const float* __restrict__ W, int kf, int g,
                                           int c, f16x8& hi, f16x8& lo) {
    union { _Float16 h[8]; f16x8 v; } th, tl;
#pragma unroll
    for (int i = 0; i < 8; ++i) {
        float wv = W[(32 * kf + 8 * g + i) * HH + c];
        _Float16 hf = (_Float16)wv;          // RNE
        th.h[i] = hf;
        tl.h[i] = (_Float16)(wv - (float)hf);
    }
    hi = th.v;
    lo = tl.v;
}

// emb2h[v][j] = fp16( b0[j] + sum_e emb[v][e] * Wx0[e][j] )  (unchanged from R8)
__global__ __launch_bounds__(256) void emb2_kernel(const float* __restrict__ emb,
                                                   const float* __restrict__ Wx0,
                                                   const float* __restrict__ b0,
                                                   _Float16* __restrict__ emb2h) {
    const int tid = threadIdx.x;
    const int wid = tid >> 6;
    const int l = tid & 63;
    const int g = l >> 4;
    const int r16 = l & 15;
    const int c = 16 * wid + r16;
    const int jcol = 16 * wid + 4 * g;
    const int vr = blockIdx.x * 16 + r16;   // VV % 16 == 0

    f16x8 wa[4];   // Wx0^T hi frags, K = 128 (zero-pad e >= 100)
#pragma unroll
    for (int kf = 0; kf < 4; ++kf) {
        union { _Float16 h[8]; f16x8 v; } t;
#pragma unroll
        for (int i = 0; i < 8; ++i) {
            int e = 32 * kf + 8 * g + i;
            t.h[i] = (e < EE) ? (_Float16)Wx0[e * HH + c] : (_Float16)0.f;
        }
        wa[kf] = t.v;
    }
    const float* er = emb + (size_t)vr * EE;
    f4v acc = *(const f4v*)&b0[jcol];
#pragma unroll
    for (int kf = 0; kf < 4; ++kf) {
        union { _Float16 h[8]; f16x8 v; } tb;
#pragma unroll
        for (int i = 0; i < 8; ++i) {
            int e = 32 * kf + 8 * g + i;
            tb.h[i] = (e < EE) ? (_Float16)er[e] : (_Float16)0.f;
        }
        acc = MFMA(wa[kf], tb.v, acc);
    }
    f16x4 o;
#pragma unroll
    for (int q = 0; q < 4; ++q) o[q] = (_Float16)acc[q];
    *(f16x4*)&emb2h[(size_t)vr * HH + jcol] = o;
}

// Layer-split pipeline: 256 blocks x 512 thr (8 waves = 2/SIMD), 16 rows/block.
// Waves 0-3 (L0, tile=w8):   h0(p)^T   = tanh(x(p)^T + Wh0^T @ h0(p-1)^T)
// Waves 4-7 (L1, tile=w8-4): h1(p-1)^T = tanh(b1 + Wx1^T @ h0(p-1)^T
//                                                 + Wh1^T @ h1(p-2)^T)
// Same total work as R8's merged form, same single BAR per phase, but each
// wave's critical path is halved and the two lockstep waves per SIMD fill
// each other's ds_read/MFMA/tanh stalls (R5 reinterpretation: 1.93x per-CU
// issue efficiency at 2 waves/SIMD).
__global__ __launch_bounds__(512, 1) void rnn_pipe(
    const int* __restrict__ tokens, const _Float16* __restrict__ emb2,
    const float* __restrict__ Wh0, const float* __restrict__ Wx1,
    const float* __restrict__ Wh1, const float* __restrict__ b1,
    const float* __restrict__ Wout, const float* __restrict__ bout,
    float* __restrict__ out) {
    __shared__ __align__(16) _Float16 H0[2][16][STR];
    __shared__ __align__(16) _Float16 H1[2][16][STR];
    __shared__ __align__(16) int tokT[TT][16];   // [t][row], byte-scaled (<<7)
    __shared__ float Pred[4][16];

    const int tid = threadIdx.x;
    const int w8 = tid >> 6;         // 0..7
    const int l = tid & 63;
    const int g = l >> 4;
    const int r16 = l & 15;          // my batch row
    const bool isL0 = (w8 < 4);
    const int tile = isL0 ? w8 : (w8 - 4);
    const int c = 16 * tile + r16;   // weight column for A-fragment loads
    const int jcol = 16 * tile + 4 * g;  // my 4 output cols
    const int R = blockIdx.x * 16;   // base batch row

    for (int i = tid; i < 16 * TT; i += 512) {
        int r = i / TT, t = i - r * TT;              // coalesced global read
        tokT[t][r] = tokens[R * TT + i] << 7;        // row stride 64 fp16 = 128 B
    }

    // Role weights: L0 -> wA = Wh0; L1 -> wA = Wx1, wB = Wh1.
    f16x8 wAh[2], wAl[2], wBh[2], wBl[2];
    if (isL0) {
        load_wfrag(Wh0, 0, g, c, wAh[0], wAl[0]);
        load_wfrag(Wh0, 1, g, c, wAh[1], wAl[1]);
        wBh[0] = wBh[1] = wBl[0] = wBl[1] = (f16x8)0;
    } else {
        load_wfrag(Wx1, 0, g, c, wAh[0], wAl[0]);
        load_wfrag(Wx1, 1, g, c, wAh[1], wAl[1]);
        load_wfrag(Wh1, 0, g, c, wBh[0], wBl[0]);
        load_wfrag(Wh1, 1, g, c, wBh[1], wBl[1]);
    }
    const f4v b1v = *(const f4v*)&b1[jcol];
    const f4v wov = *(const f4v*)&Wout[jcol];
    const f4v z4 = {0.f, 0.f, 0.f, 0.f};
    const char* ebase = (const char*)emb2 + (size_t)jcol * 2;

    BAR();   // tokens staged

    f16x8 a0[2] = {(f16x8)0, (f16x8)0};   // h0(p-1)^T fragments (kf=0,1)
    f16x8 a1[2] = {(f16x8)0, (f16x8)0};   // h1(p-2)^T fragments (L1 only)

    f16x4 xc = (f16x4)0, xn = (f16x4)0;   // raw fp16 gathers (L0 only)
    if (isL0) {
        int tb0 = tokT[0][r16];
        int tb1 = tokT[1][r16];
        xc = *(const f16x4*)(ebase + tb0);
        xn = *(const f16x4*)(ebase + tb1);
        // ---- phase 0: h0(0) = tanh(x0) ----
        f16x4 ph;
#pragma unroll
        for (int q = 0; q < 4; ++q) ph[q] = (_Float16)fast_tanh((float)xc[q]);
        *(f16x4*)&H0[0][r16][jcol] = ph;           // one b64 write
        xc = xn;
    }
    BAR();
    a0[0] = *(const f16x8*)&H0[0][r16][8 * g];
    a0[1] = *(const f16x8*)&H0[0][r16][32 + 8 * g];
    // a1 stays zero (h1(-1) = 0); H1[0] not yet written -> do not read it.

    // ---- main loop p = 1..TT-1 (par = p&1) ----
#pragma unroll 2
    for (int p = 1; p <= TT - 1; ++p) {
        const int par = p & 1;
        if (isL0) {
            // prefetch x(p+1) (clamped; x(TT-1) redundant re-gather at p=79)
            int pn = (p + 1 <= TT - 1) ? p + 1 : TT - 1;
            int tb = tokT[pn][r16];
            xn = *(const f16x4*)(ebase + tb);
            // h0(p): 2 chains of 2
            f4v A1 = {(float)xc[0], (float)xc[1], (float)xc[2], (float)xc[3]};
            A1 = MFMA(wAh[0], a0[0], A1);
            A1 = MFMA(wAh[1], a0[1], A1);
            f4v A2 = MFMA(wAl[0], a0[0], z4);
            A2 = MFMA(wAl[1], a0[1], A2);
            f4v acc0 = A1 + A2;
            f16x4 p0;
#pragma unroll
            for (int q = 0; q < 4; ++q) p0[q] = (_Float16)fast_tanh(acc0[q]);
            *(f16x4*)&H0[par][r16][jcol] = p0;
            xc = xn;
        } else {
            // h1(p-1): 4 chains of 2
            f4v C1 = b1v;
            C1 = MFMA(wAh[0], a0[0], C1);
            C1 = MFMA(wAh[1], a0[1], C1);
            f4v C2 = MFMA(wAl[0], a0[0], z4);
            C2 = MFMA(wAl[1], a0[1], C2);
            f4v C3 = MFMA(wBh[0], a1[0], z4);
            C3 = MFMA(wBh[1], a1[1], C3);
            f4v C4 = MFMA(wBl[0], a1[0], z4);
            C4 = MFMA(wBl[1], a1[1], C4);
            f4v acc1 = (C1 + C2) + (C3 + C4);
            f16x4 p1;
#pragma unroll
            for (int q = 0; q < 4; ++q) p1[q] = (_Float16)fast_tanh(acc1[q]);
            *(f16x4*)&H1[par][r16][jcol] = p1;
        }
        BAR();
        a0[0] = *(const f16x8*)&H0[par][r16][8 * g];
        a0[1] = *(const f16x8*)&H0[par][r16][32 + 8 * g];
        if (!isL0) {
            a1[0] = *(const f16x8*)&H1[par][r16][8 * g];
            a1[1] = *(const f16x8*)&H1[par][r16][32 + 8 * g];
        }
    }

    // ---- p = TT = 80: L1 only -> h1(79) stays in registers; epilogue ----
    if (!isL0) {
        f4v C1 = b1v;
        C1 = MFMA(wAh[0], a0[0], C1);
        C1 = MFMA(wAh[1], a0[1], C1);
        f4v C2 = MFMA(wAl[0], a0[0], z4);
        C2 = MFMA(wAl[1], a0[1], C2);
        f4v C3 = MFMA(wBh[0], a1[0], z4);
        C3 = MFMA(wBh[1], a1[1], C3);
        f4v C4 = MFMA(wBl[0], a1[0], z4);
        C4 = MFMA(wBl[1], a1[1], C4);
        f4v acc1 = (C1 + C2) + (C3 + C4);
        // out = sigmoid(h1(79) @ Wout + bout): lane holds 4 cols of row r16
        float pp = fast_tanh(acc1[0]) * wov[0];
        pp = fmaf(fast_tanh(acc1[1]), wov[1], pp);
        pp = fmaf(fast_tanh(acc1[2]), wov[2], pp);
        pp = fmaf(fast_tanh(acc1[3]), wov[3], pp);
        pp += __shfl_xor(pp, 16, 64);   // sum over g-groups
        pp += __shfl_xor(pp, 32, 64);
        if (l < 16) Pred[tile][l] = pp;
    }
    BAR();
    if (tid < 16) {
        float logit = Pred[0][tid] + Pred[1][tid] + Pred[2][tid] +
                      Pred[3][tid] + bout[0];
        out[R + tid] = __builtin_amdgcn_rcpf(
            1.0f + __builtin_amdgcn_exp2f(-1.4426950408889634f * logit));
    }
}

extern "C" void kernel_launch(void* const* d_in, const int* in_sizes, int n_in,
                              void* d_out, int out_size, void* d_ws, size_t ws_size,
                              hipStream_t stream) {
    const int*   tokens = (const int*)  d_in[0];
    const float* emb    = (const float*)d_in[1];
    const float* Wx0    = (const float*)d_in[2];
    const float* Wh0    = (const float*)d_in[3];
    const float* b0     = (const float*)d_in[4];
    const float* Wx1    = (const float*)d_in[5];
    const float* Wh1    = (const float*)d_in[6];
    const float* b1     = (const float*)d_in[7];
    const float* Wout   = (const float*)d_in[8];
    const float* bout   = (const float*)d_in[9];
    float* out  = (float*)d_out;
    _Float16* emb2h = (_Float16*)d_ws;   // VV*HH fp16 = 1.28 MB

    emb2_kernel<<<VV / 16, 256, 0, stream>>>(emb, Wx0, b0, emb2h);
    rnn_pipe<<<BB / 16, 512, 0, stream>>>(tokens, emb2h, Wh0, Wx1, Wh1, b1,
                                          Wout, bout, out);
}